// Round 2
// baseline (563.716 us; speedup 1.0000x reference)
//
#include <hip/hip_runtime.h>
#include <cstdint>

typedef __bf16 bf16_t;
typedef __bf16 bf16x8 __attribute__((ext_vector_type(8)));
typedef float f32x4 __attribute__((ext_vector_type(4)));

// ---- geometry constants ----
#define BT_   128
#define LTOK  197
#define CIN   768
#define CA_   384
#define TT    16
#define HH    14
#define NTOK  25088   // 128*196

__device__ __forceinline__ void gl_lds16(const void* g, void* l) {
  __builtin_amdgcn_global_load_lds(
      (const __attribute__((address_space(1))) unsigned int*)g,
      (__attribute__((address_space(3))) unsigned int*)l,
      16, 0, 0);
}

// ---------------- prep: fold 3 convs + identity into one 3x3x3 kernel (transposed layouts) ----------------
__global__ void prep_weights_kernel(
    const float* __restrict__ c1w, const float* __restrict__ c1b,
    const float* __restrict__ c2w, const float* __restrict__ c2b,
    const float* __restrict__ c3w, const float* __restrict__ c3b,
    const float* __restrict__ projw,
    float* __restrict__ Wt,      // [27][384]
    float* __restrict__ beff,    // [384]
    float* __restrict__ pwt) {   // [3][384]
  int a = blockIdx.x * blockDim.x + threadIdx.x;
  if (a >= CA_) return;
  for (int dt = 0; dt < 3; dt++)
    for (int dh = 0; dh < 3; dh++)
      for (int dw = 0; dw < 3; dw++) {
        float v = c3w[a*27 + dt*9 + dh*3 + dw];
        if (dh == 1 && dw == 1) v += c1w[a*3 + dt];
        if (dt == 1)            v += c2w[a*9 + dh*3 + dw];
        v *= (1.0f/3.0f);
        if (dt == 1 && dh == 1 && dw == 1) v += 1.0f;   // + identity
        Wt[((dt*3+dh)*3+dw)*CA_ + a] = v;
      }
  beff[a] = (c1b[a] + c2b[a] + c3b[a]) * (1.0f/3.0f);
  pwt[0*CA_ + a] = projw[a*3 + 0];
  pwt[1*CA_ + a] = projw[a*3 + 1];
  pwt[2*CA_ + a] = projw[a*3 + 2];
}

// convert fc weights to bf16 + copy the CLS rows of x into out (fused elementwise)
__global__ void convert_w_kernel(const float* __restrict__ fc1w,
                                 const float* __restrict__ fc2w,
                                 const float* __restrict__ x,
                                 float* __restrict__ out,
                                 bf16_t* __restrict__ W1,
                                 bf16_t* __restrict__ W2) {
  int i = blockIdx.x * blockDim.x + threadIdx.x;
  if (i < CA_*CIN) { W1[i] = (bf16_t)fc1w[i]; return; }
  i -= CA_*CIN;
  if (i < CIN*CA_) { W2[i] = (bf16_t)fc2w[i]; return; }
  i -= CIN*CA_;
  if (i < BT_*CIN) {
    int bt = i / CIN, c = i % CIN;
    size_t off = (size_t)bt * LTOK * CIN + c;
    out[off] = x[off];
  }
}

// ---------------- GEMM1: H0[tok,a] = bf16( x_tokens[tok,:] . fc1_w[a,:] + fc1_b[a] ) ----------------
__global__ __launch_bounds__(256) void gemm1_kernel(
    const float* __restrict__ x, const bf16_t* __restrict__ W1,
    const float* __restrict__ fc1b, bf16_t* __restrict__ H0) {
  __shared__ bf16_t Alds[128*32];
  __shared__ bf16_t Blds[128*32];
  const int tid  = threadIdx.x;
  const int lane = tid & 63;
  const int wave = tid >> 6;
  const int bm = blockIdx.x, bn = blockIdx.y;

  const int arow  = tid >> 1;
  const int kbase = (tid & 1) * 16;
  const int tok   = bm*128 + arow;
  const int bt    = tok / 196;
  const float* xrow = x + (size_t)(tok + bt + 1) * CIN + kbase;
  bf16_t* alds_dst = &Alds[arow*32 + kbase];

  const bf16_t* bsrc0 = W1 + (size_t)(bn*128 + (tid>>2))*CIN + (tid&3)*8;
  const bf16_t* bsrc1 = bsrc0 + (size_t)64*CIN;
  bf16_t* blds0 = &Blds[tid*8];
  bf16_t* blds1 = &Blds[(tid+256)*8];

  const int quad = lane >> 4;
  const int r16  = lane & 15;
  const int wm = (wave >> 1) * 64;
  const int wn = (wave & 1) * 64;

  f32x4 acc[4][4] = {};

  for (int k0 = 0; k0 < CIN; k0 += 32) {
    gl_lds16(bsrc0 + k0, blds0);
    gl_lds16(bsrc1 + k0, blds1);
    const float4* xp = (const float4*)(xrow + k0);
    float4 f0 = xp[0], f1 = xp[1], f2 = xp[2], f3 = xp[3];
    bf16x8 p0, p1;
    p0[0]=(bf16_t)f0.x; p0[1]=(bf16_t)f0.y; p0[2]=(bf16_t)f0.z; p0[3]=(bf16_t)f0.w;
    p0[4]=(bf16_t)f1.x; p0[5]=(bf16_t)f1.y; p0[6]=(bf16_t)f1.z; p0[7]=(bf16_t)f1.w;
    p1[0]=(bf16_t)f2.x; p1[1]=(bf16_t)f2.y; p1[2]=(bf16_t)f2.z; p1[3]=(bf16_t)f2.w;
    p1[4]=(bf16_t)f3.x; p1[5]=(bf16_t)f3.y; p1[6]=(bf16_t)f3.z; p1[7]=(bf16_t)f3.w;
    *(bf16x8*)alds_dst       = p0;
    *(bf16x8*)(alds_dst + 8) = p1;
    __syncthreads();
    bf16x8 af[4], bfr[4];
    #pragma unroll
    for (int mt = 0; mt < 4; mt++)
      af[mt] = *(const bf16x8*)&Alds[(wm + mt*16 + r16)*32 + quad*8];
    #pragma unroll
    for (int nt = 0; nt < 4; nt++)
      bfr[nt] = *(const bf16x8*)&Blds[(wn + nt*16 + r16)*32 + quad*8];
    #pragma unroll
    for (int mt = 0; mt < 4; mt++)
      #pragma unroll
      for (int nt = 0; nt < 4; nt++)
        acc[mt][nt] = __builtin_amdgcn_mfma_f32_16x16x32_bf16(af[mt], bfr[nt], acc[mt][nt], 0, 0, 0);
    __syncthreads();
  }

  #pragma unroll
  for (int nt = 0; nt < 4; nt++) {
    const int col = bn*128 + wn + nt*16 + r16;
    const float bias = fc1b[col];
    #pragma unroll
    for (int mt = 0; mt < 4; mt++) {
      const int row0 = bm*128 + wm + mt*16 + quad*4;
      #pragma unroll
      for (int rg = 0; rg < 4; rg++)
        H0[(size_t)(row0 + rg)*CA_ + col] = (bf16_t)(acc[mt][nt][rg] + bias);
    }
  }
}

// ---------------- fused conv v2: vectorized 8-ch/thread, t-parallel, LDS y-exchange ----------------
// block = one (b,hw) column; 768 threads = (t in 16) x (cg in 48); thread owns 8 channels.
__global__ __launch_bounds__(768) void conv_kernel(
    const bf16_t* __restrict__ H0,
    const float* __restrict__ Wt,     // [27][384]
    const float* __restrict__ beff,   // [384]
    const float* __restrict__ pwt,    // [3][384]
    const float* __restrict__ pb,     // [384]
    bf16_t* __restrict__ Z) {
  __shared__ float Wlds[27*CA_];   // 41472 B
  __shared__ float ylds[TT*CA_];   // 24576 B

  const int tid = threadIdx.x;
  // stage transposed weights (contiguous, coalesced)
  for (int i = tid; i < 27*CA_; i += 768) Wlds[i] = Wt[i];

  const int blk = blockIdx.x;            // 0..1567
  const int b   = blk / 196;
  const int hw  = blk % 196;
  const int h   = hw / HH;
  const int w   = hw % HH;
  const int t   = tid / 48;
  const int cg  = tid % 48;
  const int c0  = cg * 8;

  float y[8];
  #pragma unroll
  for (int c = 0; c < 8; c++) y[c] = beff[c0 + c];

  __syncthreads();   // Wlds ready

  const bf16_t* base = H0 + ((size_t)(b*TT)*196)*CA_ + c0;

  #pragma unroll
  for (int dt = 0; dt < 3; dt++) {
    const int tau = t + dt - 1;
    const bool tok_t = (tau >= 0) && (tau < TT);
    #pragma unroll
    for (int dh = 0; dh < 3; dh++) {
      const int h2 = h + dh - 1;
      #pragma unroll
      for (int dw = 0; dw < 3; dw++) {
        const int w2 = w + dw - 1;
        const bool ok = tok_t && (h2 >= 0) && (h2 < HH) && (w2 >= 0) && (w2 < HH);
        bf16x8 g = {};
        if (ok)
          g = *(const bf16x8*)(base + ((size_t)tau*196 + h2*HH + w2)*CA_);
        const float* wv = &Wlds[((dt*3+dh)*3+dw)*CA_ + c0];
        #pragma unroll
        for (int c = 0; c < 8; c++)
          y[c] += (float)g[c] * wv[c];
      }
    }
  }

  // publish y for temporal proj exchange
  #pragma unroll
  for (int c = 0; c < 8; c++) ylds[t*CA_ + c0 + c] = y[c];
  __syncthreads();

  float p0v[8], p1v[8], p2v[8], pbv[8];
  #pragma unroll
  for (int c = 0; c < 8; c++) {
    p0v[c] = pwt[0*CA_ + c0 + c];
    p1v[c] = pwt[1*CA_ + c0 + c];
    p2v[c] = pwt[2*CA_ + c0 + c];
    pbv[c] = pb[c0 + c];
  }

  bf16x8 zo;
  #pragma unroll
  for (int c = 0; c < 8; c++) {
    const float ym = (t > 0)    ? ylds[(t-1)*CA_ + c0 + c] : 0.f;
    const float yp = (t < TT-1) ? ylds[(t+1)*CA_ + c0 + c] : 0.f;
    const float z  = y[c] + pbv[c] + p0v[c]*ym + p1v[c]*y[c] + p2v[c]*yp;
    zo[c] = (bf16_t)z;
  }
  *(bf16x8*)(Z + ((size_t)(b*TT + t)*196 + hw)*CA_ + c0) = zo;
}

// ---------------- GEMM2: out[xrow,c] = x[xrow,c] + Z[tok,:] . fc2_w[c,:] + fc2_b[c] ----------------
__global__ __launch_bounds__(256) void gemm2_kernel(
    const bf16_t* __restrict__ Z, const bf16_t* __restrict__ W2,
    const float* __restrict__ fc2b, const float* __restrict__ x,
    float* __restrict__ out) {
  __shared__ bf16_t Alds[128*32];
  __shared__ bf16_t Blds[128*32];
  const int tid  = threadIdx.x;
  const int lane = tid & 63;
  const int wave = tid >> 6;
  const int bm = blockIdx.x, bn = blockIdx.y;

  const bf16_t* asrc0 = Z  + (size_t)(bm*128 + (tid>>2))*CA_ + (tid&3)*8;
  const bf16_t* asrc1 = asrc0 + (size_t)64*CA_;
  const bf16_t* bsrc0 = W2 + (size_t)(bn*128 + (tid>>2))*CA_ + (tid&3)*8;
  const bf16_t* bsrc1 = bsrc0 + (size_t)64*CA_;
  bf16_t* alds0 = &Alds[tid*8];
  bf16_t* alds1 = &Alds[(tid+256)*8];
  bf16_t* blds0 = &Blds[tid*8];
  bf16_t* blds1 = &Blds[(tid+256)*8];

  const int quad = lane >> 4;
  const int r16  = lane & 15;
  const int wm = (wave >> 1) * 64;
  const int wn = (wave & 1) * 64;

  f32x4 acc[4][4] = {};

  for (int k0 = 0; k0 < CA_; k0 += 32) {
    gl_lds16(asrc0 + k0, alds0);
    gl_lds16(asrc1 + k0, alds1);
    gl_lds16(bsrc0 + k0, blds0);
    gl_lds16(bsrc1 + k0, blds1);
    __syncthreads();
    bf16x8 af[4], bfr[4];
    #pragma unroll
    for (int mt = 0; mt < 4; mt++)
      af[mt] = *(const bf16x8*)&Alds[(wm + mt*16 + r16)*32 + quad*8];
    #pragma unroll
    for (int nt = 0; nt < 4; nt++)
      bfr[nt] = *(const bf16x8*)&Blds[(wn + nt*16 + r16)*32 + quad*8];
    #pragma unroll
    for (int mt = 0; mt < 4; mt++)
      #pragma unroll
      for (int nt = 0; nt < 4; nt++)
        acc[mt][nt] = __builtin_amdgcn_mfma_f32_16x16x32_bf16(af[mt], bfr[nt], acc[mt][nt], 0, 0, 0);
    __syncthreads();
  }

  #pragma unroll
  for (int nt = 0; nt < 4; nt++) {
    const int col = bn*128 + wn + nt*16 + r16;
    const float bias = fc2b[col];
    #pragma unroll
    for (int mt = 0; mt < 4; mt++) {
      #pragma unroll
      for (int rg = 0; rg < 4; rg++) {
        const int tok = bm*128 + wm + mt*16 + quad*4 + rg;
        const int bt  = tok / 196;
        const size_t o = (size_t)(tok + bt + 1)*CIN + col;
        out[o] = x[o] + acc[mt][nt][rg] + bias;
      }
    }
  }
}

extern "C" void kernel_launch(void* const* d_in, const int* in_sizes, int n_in,
                              void* d_out, int out_size, void* d_ws, size_t ws_size,
                              hipStream_t stream) {
  (void)in_sizes; (void)n_in; (void)out_size; (void)ws_size;
  const float* x    = (const float*)d_in[0];
  const float* fc1w = (const float*)d_in[1];
  const float* fc1b = (const float*)d_in[2];
  const float* c1w  = (const float*)d_in[3];
  const float* c1b  = (const float*)d_in[4];
  const float* c2w  = (const float*)d_in[5];
  const float* c2b  = (const float*)d_in[6];
  const float* c3w  = (const float*)d_in[7];
  const float* c3b  = (const float*)d_in[8];
  const float* pw   = (const float*)d_in[9];
  const float* pb   = (const float*)d_in[10];
  const float* fc2w = (const float*)d_in[11];
  const float* fc2b = (const float*)d_in[12];
  float* out = (float*)d_out;

  char* ws = (char*)d_ws;
  bf16_t* W1   = (bf16_t*)(ws);                    // 589824
  bf16_t* W2   = (bf16_t*)(ws + 589824);           // 589824
  float*  Wt   = (float*) (ws + 1179648);          // 27*384*4 = 41472
  float*  beff = (float*) (ws + 1221120);          // 1536
  float*  pwt  = (float*) (ws + 1222656);          // 3*384*4 = 4608
  bf16_t* H0   = (bf16_t*)(ws + 1227264);          // 19267584
  bf16_t* Z    = (bf16_t*)(ws + 20494848);         // 19267584
  // total ws use: 39762432 bytes

  prep_weights_kernel<<<dim3(2), dim3(192), 0, stream>>>(
      c1w, c1b, c2w, c2b, c3w, c3b, pw, Wt, beff, pwt);
  convert_w_kernel<<<dim3(2688), dim3(256), 0, stream>>>(fc1w, fc2w, x, out, W1, W2);
  gemm1_kernel<<<dim3(196, 3), dim3(256), 0, stream>>>(x, W1, fc1b, H0);
  conv_kernel<<<dim3(1568), dim3(768), 0, stream>>>(H0, Wt, beff, pwt, pb, Z);
  gemm2_kernel<<<dim3(196, 6), dim3(256), 0, stream>>>(Z, W2, fc2b, x, out);
}

// Round 3
// 354.922 us; speedup vs baseline: 1.5883x; 1.5883x over previous
//
#include <hip/hip_runtime.h>
#include <cstdint>

typedef __bf16 bf16_t;
typedef __bf16 bf16x8 __attribute__((ext_vector_type(8)));
typedef float f32x4 __attribute__((ext_vector_type(4)));

// ---- geometry constants ----
#define BT_   128
#define LTOK  197
#define CIN   768
#define CA_   384
#define TT    16
#define HH    14
#define NTOK  25088   // 128*196

__device__ __forceinline__ void gl_lds16(const void* g, void* l) {
  __builtin_amdgcn_global_load_lds(
      (const __attribute__((address_space(1))) unsigned int*)g,
      (__attribute__((address_space(3))) unsigned int*)l,
      16, 0, 0);
}

// ---------------- prep: fold 3 convs + identity into one 3x3x3 kernel ----------------
// Wtb: bf16 [27][384] (tap-major, channel-contiguous); pwt: f32 [3][384]
__global__ void prep_weights_kernel(
    const float* __restrict__ c1w, const float* __restrict__ c1b,
    const float* __restrict__ c2w, const float* __restrict__ c2b,
    const float* __restrict__ c3w, const float* __restrict__ c3b,
    const float* __restrict__ projw,
    bf16_t* __restrict__ Wtb,    // [27][384]
    float* __restrict__ beff,    // [384]
    float* __restrict__ pwt) {   // [3][384]
  int a = blockIdx.x * blockDim.x + threadIdx.x;
  if (a >= CA_) return;
  for (int dt = 0; dt < 3; dt++)
    for (int dh = 0; dh < 3; dh++)
      for (int dw = 0; dw < 3; dw++) {
        float v = c3w[a*27 + dt*9 + dh*3 + dw];
        if (dh == 1 && dw == 1) v += c1w[a*3 + dt];
        if (dt == 1)            v += c2w[a*9 + dh*3 + dw];
        v *= (1.0f/3.0f);
        if (dt == 1 && dh == 1 && dw == 1) v += 1.0f;   // + identity
        Wtb[((dt*3+dh)*3+dw)*CA_ + a] = (bf16_t)v;
      }
  beff[a] = (c1b[a] + c2b[a] + c3b[a]) * (1.0f/3.0f);
  pwt[0*CA_ + a] = projw[a*3 + 0];
  pwt[1*CA_ + a] = projw[a*3 + 1];
  pwt[2*CA_ + a] = projw[a*3 + 2];
}

// convert fc weights to bf16 + copy the CLS rows of x into out (fused elementwise)
__global__ void convert_w_kernel(const float* __restrict__ fc1w,
                                 const float* __restrict__ fc2w,
                                 const float* __restrict__ x,
                                 float* __restrict__ out,
                                 bf16_t* __restrict__ W1,
                                 bf16_t* __restrict__ W2) {
  int i = blockIdx.x * blockDim.x + threadIdx.x;
  if (i < CA_*CIN) { W1[i] = (bf16_t)fc1w[i]; return; }
  i -= CA_*CIN;
  if (i < CIN*CA_) { W2[i] = (bf16_t)fc2w[i]; return; }
  i -= CIN*CA_;
  if (i < BT_*CIN) {
    int bt = i / CIN, c = i % CIN;
    size_t off = (size_t)bt * LTOK * CIN + c;
    out[off] = x[off];
  }
}

// ---------------- GEMM1: H0[tok,a] = bf16( x_tokens[tok,:] . fc1_w[a,:] + fc1_b[a] ) ----------------
__global__ __launch_bounds__(256) void gemm1_kernel(
    const float* __restrict__ x, const bf16_t* __restrict__ W1,
    const float* __restrict__ fc1b, bf16_t* __restrict__ H0) {
  __shared__ bf16_t Alds[128*32];
  __shared__ bf16_t Blds[128*32];
  const int tid  = threadIdx.x;
  const int lane = tid & 63;
  const int wave = tid >> 6;
  const int bm = blockIdx.x, bn = blockIdx.y;

  const int arow  = tid >> 1;
  const int kbase = (tid & 1) * 16;
  const int tok   = bm*128 + arow;
  const int bt    = tok / 196;
  const float* xrow = x + (size_t)(tok + bt + 1) * CIN + kbase;
  bf16_t* alds_dst = &Alds[arow*32 + kbase];

  const bf16_t* bsrc0 = W1 + (size_t)(bn*128 + (tid>>2))*CIN + (tid&3)*8;
  const bf16_t* bsrc1 = bsrc0 + (size_t)64*CIN;
  bf16_t* blds0 = &Blds[tid*8];
  bf16_t* blds1 = &Blds[(tid+256)*8];

  const int quad = lane >> 4;
  const int r16  = lane & 15;
  const int wm = (wave >> 1) * 64;
  const int wn = (wave & 1) * 64;

  f32x4 acc[4][4] = {};

  for (int k0 = 0; k0 < CIN; k0 += 32) {
    gl_lds16(bsrc0 + k0, blds0);
    gl_lds16(bsrc1 + k0, blds1);
    const float4* xp = (const float4*)(xrow + k0);
    float4 f0 = xp[0], f1 = xp[1], f2 = xp[2], f3 = xp[3];
    bf16x8 p0, p1;
    p0[0]=(bf16_t)f0.x; p0[1]=(bf16_t)f0.y; p0[2]=(bf16_t)f0.z; p0[3]=(bf16_t)f0.w;
    p0[4]=(bf16_t)f1.x; p0[5]=(bf16_t)f1.y; p0[6]=(bf16_t)f1.z; p0[7]=(bf16_t)f1.w;
    p1[0]=(bf16_t)f2.x; p1[1]=(bf16_t)f2.y; p1[2]=(bf16_t)f2.z; p1[3]=(bf16_t)f2.w;
    p1[4]=(bf16_t)f3.x; p1[5]=(bf16_t)f3.y; p1[6]=(bf16_t)f3.z; p1[7]=(bf16_t)f3.w;
    *(bf16x8*)alds_dst       = p0;
    *(bf16x8*)(alds_dst + 8) = p1;
    __syncthreads();
    bf16x8 af[4], bfr[4];
    #pragma unroll
    for (int mt = 0; mt < 4; mt++)
      af[mt] = *(const bf16x8*)&Alds[(wm + mt*16 + r16)*32 + quad*8];
    #pragma unroll
    for (int nt = 0; nt < 4; nt++)
      bfr[nt] = *(const bf16x8*)&Blds[(wn + nt*16 + r16)*32 + quad*8];
    #pragma unroll
    for (int mt = 0; mt < 4; mt++)
      #pragma unroll
      for (int nt = 0; nt < 4; nt++)
        acc[mt][nt] = __builtin_amdgcn_mfma_f32_16x16x32_bf16(af[mt], bfr[nt], acc[mt][nt], 0, 0, 0);
    __syncthreads();
  }

  #pragma unroll
  for (int nt = 0; nt < 4; nt++) {
    const int col = bn*128 + wn + nt*16 + r16;
    const float bias = fc1b[col];
    #pragma unroll
    for (int mt = 0; mt < 4; mt++) {
      const int row0 = bm*128 + wm + mt*16 + quad*4;
      #pragma unroll
      for (int rg = 0; rg < 4; rg++)
        H0[(size_t)(row0 + rg)*CA_ + col] = (bf16_t)(acc[mt][nt][rg] + bias);
    }
  }
}

// ---------------- fused conv v3: scatter-in-t, 9 unconditional taps/thread ----------------
// block = one (b,hw) column; 768 threads = (t in 16) x (cg in 48); thread owns 8 channels at tau=t.
// s0 -> output t+1, s1 -> output t, s2 -> output t-1 (exchanged through LDS).
__global__ __launch_bounds__(768, 3) void conv_kernel(
    const bf16_t* __restrict__ H0,
    const bf16_t* __restrict__ Wtb,   // [27][384] bf16
    const float* __restrict__ beff,   // [384]
    const float* __restrict__ pwt,    // [3][384]
    const float* __restrict__ pb,     // [384]
    bf16_t* __restrict__ Z) {
  __shared__ bf16_t Wlds[27*CA_];  // 20736 B
  __shared__ float exA[TT*CA_];    // 24576 B
  __shared__ float exB[TT*CA_];    // 24576 B

  const int tid = threadIdx.x;
  {
    const uint32_t* src = (const uint32_t*)Wtb;
    uint32_t* dst = (uint32_t*)Wlds;
    #pragma unroll
    for (int i = 0; i < 7; i++) {
      int idx = tid + i*768;
      if (idx < 27*CA_/2) dst[idx] = src[idx];
    }
  }

  const int blk = blockIdx.x;            // 0..1567
  const int b   = blk / 196;
  const int hw  = blk % 196;
  const int h   = hw / HH;
  const int w   = hw % HH;
  const int t   = tid / 48;
  const int cg  = tid % 48;
  const int c0  = cg * 8;

  // load the 9 spatial taps at tau = t, unconditionally from clamped (in-bounds) addresses
  const bf16_t* rowbase = H0 + ((size_t)(b*TT + t)*196)*CA_ + c0;
  bf16x8 g[9];
  float  m[9];
  #pragma unroll
  for (int dh = 0; dh < 3; dh++) {
    #pragma unroll
    for (int dw = 0; dw < 3; dw++) {
      const int h2 = h + dh - 1, w2 = w + dw - 1;
      const bool ok = ((unsigned)h2 < HH) && ((unsigned)w2 < HH);
      const int h2c = ok ? h2 : h;
      const int w2c = ok ? w2 : w;
      g[dh*3+dw] = *(const bf16x8*)(rowbase + (h2c*HH + w2c)*CA_);
      m[dh*3+dw] = ok ? 1.0f : 0.0f;
    }
  }

  __syncthreads();   // Wlds ready

  float s0[8] = {}, s1[8] = {}, s2[8] = {};
  #pragma unroll
  for (int j = 0; j < 9; j++) {
    float gf[8];
    #pragma unroll
    for (int c = 0; c < 8; c++) gf[c] = m[j] * (float)g[j][c];
    const bf16x8 w0 = *(const bf16x8*)&Wlds[(0*9+j)*CA_ + c0];
    const bf16x8 w1 = *(const bf16x8*)&Wlds[(1*9+j)*CA_ + c0];
    const bf16x8 w2 = *(const bf16x8*)&Wlds[(2*9+j)*CA_ + c0];
    #pragma unroll
    for (int c = 0; c < 8; c++) {
      s0[c] += gf[c] * (float)w0[c];
      s1[c] += gf[c] * (float)w1[c];
      s2[c] += gf[c] * (float)w2[c];
    }
  }

  // exchange s0 (to t+1) and s2 (to t-1); swizzled layout: addr = t*384 + k*48 + cg (lane-consecutive)
  #pragma unroll
  for (int k = 0; k < 8; k++) {
    exA[t*CA_ + k*48 + cg] = s0[k];
    exB[t*CA_ + k*48 + cg] = s2[k];
  }
  __syncthreads();

  float y[8];
  #pragma unroll
  for (int k = 0; k < 8; k++) {
    float acc = beff[c0 + k] + s1[k];
    if (t > 0)     acc += exA[(t-1)*CA_ + k*48 + cg];
    if (t < TT-1)  acc += exB[(t+1)*CA_ + k*48 + cg];
    y[k] = acc;
  }
  __syncthreads();   // all reads of exA/exB done

  // publish y for the temporal proj
  #pragma unroll
  for (int k = 0; k < 8; k++) exA[t*CA_ + k*48 + cg] = y[k];
  __syncthreads();

  bf16x8 zo;
  #pragma unroll
  for (int k = 0; k < 8; k++) {
    const float ym = (t > 0)    ? exA[(t-1)*CA_ + k*48 + cg] : 0.f;
    const float yp = (t < TT-1) ? exA[(t+1)*CA_ + k*48 + cg] : 0.f;
    const float z  = y[k] + pb[c0+k]
                   + pwt[0*CA_ + c0 + k] * ym
                   + pwt[1*CA_ + c0 + k] * y[k]
                   + pwt[2*CA_ + c0 + k] * yp;
    zo[k] = (bf16_t)z;
  }
  *(bf16x8*)(Z + ((size_t)(b*TT + t)*196 + hw)*CA_ + c0) = zo;
}

// ---------------- GEMM2: out[xrow,c] = x[xrow,c] + Z[tok,:] . fc2_w[c,:] + fc2_b[c] ----------------
__global__ __launch_bounds__(256) void gemm2_kernel(
    const bf16_t* __restrict__ Z, const bf16_t* __restrict__ W2,
    const float* __restrict__ fc2b, const float* __restrict__ x,
    float* __restrict__ out) {
  __shared__ bf16_t Alds[128*32];
  __shared__ bf16_t Blds[128*32];
  const int tid  = threadIdx.x;
  const int lane = tid & 63;
  const int wave = tid >> 6;
  const int bm = blockIdx.x, bn = blockIdx.y;

  const bf16_t* asrc0 = Z  + (size_t)(bm*128 + (tid>>2))*CA_ + (tid&3)*8;
  const bf16_t* asrc1 = asrc0 + (size_t)64*CA_;
  const bf16_t* bsrc0 = W2 + (size_t)(bn*128 + (tid>>2))*CA_ + (tid&3)*8;
  const bf16_t* bsrc1 = bsrc0 + (size_t)64*CA_;
  bf16_t* alds0 = &Alds[tid*8];
  bf16_t* alds1 = &Alds[(tid+256)*8];
  bf16_t* blds0 = &Blds[tid*8];
  bf16_t* blds1 = &Blds[(tid+256)*8];

  const int quad = lane >> 4;
  const int r16  = lane & 15;
  const int wm = (wave >> 1) * 64;
  const int wn = (wave & 1) * 64;

  f32x4 acc[4][4] = {};

  for (int k0 = 0; k0 < CA_; k0 += 32) {
    gl_lds16(asrc0 + k0, alds0);
    gl_lds16(asrc1 + k0, alds1);
    gl_lds16(bsrc0 + k0, blds0);
    gl_lds16(bsrc1 + k0, blds1);
    __syncthreads();
    bf16x8 af[4], bfr[4];
    #pragma unroll
    for (int mt = 0; mt < 4; mt++)
      af[mt] = *(const bf16x8*)&Alds[(wm + mt*16 + r16)*32 + quad*8];
    #pragma unroll
    for (int nt = 0; nt < 4; nt++)
      bfr[nt] = *(const bf16x8*)&Blds[(wn + nt*16 + r16)*32 + quad*8];
    #pragma unroll
    for (int mt = 0; mt < 4; mt++)
      #pragma unroll
      for (int nt = 0; nt < 4; nt++)
        acc[mt][nt] = __builtin_amdgcn_mfma_f32_16x16x32_bf16(af[mt], bfr[nt], acc[mt][nt], 0, 0, 0);
    __syncthreads();
  }

  #pragma unroll
  for (int nt = 0; nt < 4; nt++) {
    const int col = bn*128 + wn + nt*16 + r16;
    const float bias = fc2b[col];
    #pragma unroll
    for (int mt = 0; mt < 4; mt++) {
      #pragma unroll
      for (int rg = 0; rg < 4; rg++) {
        const int tok = bm*128 + wm + mt*16 + quad*4 + rg;
        const int bt  = tok / 196;
        const size_t o = (size_t)(tok + bt + 1)*CIN + col;
        out[o] = x[o] + acc[mt][nt][rg] + bias;
      }
    }
  }
}

extern "C" void kernel_launch(void* const* d_in, const int* in_sizes, int n_in,
                              void* d_out, int out_size, void* d_ws, size_t ws_size,
                              hipStream_t stream) {
  (void)in_sizes; (void)n_in; (void)out_size; (void)ws_size;
  const float* x    = (const float*)d_in[0];
  const float* fc1w = (const float*)d_in[1];
  const float* fc1b = (const float*)d_in[2];
  const float* c1w  = (const float*)d_in[3];
  const float* c1b  = (const float*)d_in[4];
  const float* c2w  = (const float*)d_in[5];
  const float* c2b  = (const float*)d_in[6];
  const float* c3w  = (const float*)d_in[7];
  const float* c3b  = (const float*)d_in[8];
  const float* pw   = (const float*)d_in[9];
  const float* pb   = (const float*)d_in[10];
  const float* fc2w = (const float*)d_in[11];
  const float* fc2b = (const float*)d_in[12];
  float* out = (float*)d_out;

  char* ws = (char*)d_ws;
  bf16_t* W1   = (bf16_t*)(ws);                    // 589824
  bf16_t* W2   = (bf16_t*)(ws + 589824);           // 589824
  bf16_t* Wtb  = (bf16_t*)(ws + 1179648);          // 27*384*2 = 20736
  float*  beff = (float*) (ws + 1200384);          // 1536
  float*  pwt  = (float*) (ws + 1201920);          // 4608
  bf16_t* H0   = (bf16_t*)(ws + 1206528);          // 19267584
  bf16_t* Z    = (bf16_t*)(ws + 20474112);         // 19267584
  // total ws use: 39741696 bytes

  prep_weights_kernel<<<dim3(2), dim3(192), 0, stream>>>(
      c1w, c1b, c2w, c2b, c3w, c3b, pw, Wtb, beff, pwt);
  convert_w_kernel<<<dim3(2688), dim3(256), 0, stream>>>(fc1w, fc2w, x, out, W1, W2);
  gemm1_kernel<<<dim3(196, 3), dim3(256), 0, stream>>>(x, W1, fc1b, H0);
  conv_kernel<<<dim3(1568), dim3(768), 0, stream>>>(H0, Wtb, beff, pwt, pb, Z);
  gemm2_kernel<<<dim3(196, 6), dim3(256), 0, stream>>>(Z, W2, fc2b, x, out);
}

// Round 5
// 262.704 us; speedup vs baseline: 2.1458x; 1.3510x over previous
//
#include <hip/hip_runtime.h>
#include <cstdint>

typedef __bf16 bf16_t;
typedef __bf16 bf16x8 __attribute__((ext_vector_type(8)));
typedef float f32x4 __attribute__((ext_vector_type(4)));

// ---- geometry constants ----
#define BT_   128
#define LTOK  197
#define CIN   768
#define CA_   384
#define TT    16
#define HH    14
#define NTOK  25088   // 128*196

__device__ __forceinline__ void gl_lds16(const void* g, void* l) {
  __builtin_amdgcn_global_load_lds(
      (const __attribute__((address_space(1))) unsigned int*)g,
      (__attribute__((address_space(3))) unsigned int*)l,
      16, 0, 0);
}

// ---------------- prep: fold 3 convs + identity into one 3x3x3 kernel ----------------
// Wtb: bf16 [27][384] (tap-major, channel-contiguous); pwt: f32 [3][384]
__global__ void prep_weights_kernel(
    const float* __restrict__ c1w, const float* __restrict__ c1b,
    const float* __restrict__ c2w, const float* __restrict__ c2b,
    const float* __restrict__ c3w, const float* __restrict__ c3b,
    const float* __restrict__ projw,
    bf16_t* __restrict__ Wtb,    // [27][384]
    float* __restrict__ beff,    // [384]
    float* __restrict__ pwt) {   // [3][384]
  int a = blockIdx.x * blockDim.x + threadIdx.x;
  if (a >= CA_) return;
  for (int dt = 0; dt < 3; dt++)
    for (int dh = 0; dh < 3; dh++)
      for (int dw = 0; dw < 3; dw++) {
        float v = c3w[a*27 + dt*9 + dh*3 + dw];
        if (dh == 1 && dw == 1) v += c1w[a*3 + dt];
        if (dt == 1)            v += c2w[a*9 + dh*3 + dw];
        v *= (1.0f/3.0f);
        if (dt == 1 && dh == 1 && dw == 1) v += 1.0f;   // + identity
        Wtb[((dt*3+dh)*3+dw)*CA_ + a] = (bf16_t)v;
      }
  beff[a] = (c1b[a] + c2b[a] + c3b[a]) * (1.0f/3.0f);
  pwt[0*CA_ + a] = projw[a*3 + 0];
  pwt[1*CA_ + a] = projw[a*3 + 1];
  pwt[2*CA_ + a] = projw[a*3 + 2];
}

// convert fc weights to bf16 + copy the CLS rows of x into out (fused elementwise)
__global__ void convert_w_kernel(const float* __restrict__ fc1w,
                                 const float* __restrict__ fc2w,
                                 const float* __restrict__ x,
                                 float* __restrict__ out,
                                 bf16_t* __restrict__ W1,
                                 bf16_t* __restrict__ W2) {
  int i = blockIdx.x * blockDim.x + threadIdx.x;
  if (i < CA_*CIN) { W1[i] = (bf16_t)fc1w[i]; return; }
  i -= CA_*CIN;
  if (i < CIN*CA_) { W2[i] = (bf16_t)fc2w[i]; return; }
  i -= CIN*CA_;
  if (i < BT_*CIN) {
    int bt = i / CIN, c = i % CIN;
    size_t off = (size_t)bt * LTOK * CIN + c;
    out[off] = x[off];
  }
}

// ---------------- GEMM1: H0[tok,a] = bf16( x_tokens[tok,:] . fc1_w[a,:] + fc1_b[a] ) ----------------
__global__ __launch_bounds__(256) void gemm1_kernel(
    const float* __restrict__ x, const bf16_t* __restrict__ W1,
    const float* __restrict__ fc1b, bf16_t* __restrict__ H0) {
  __shared__ bf16_t Alds[128*32];
  __shared__ bf16_t Blds[128*32];
  const int tid  = threadIdx.x;
  const int lane = tid & 63;
  const int wave = tid >> 6;
  const int bm = blockIdx.x, bn = blockIdx.y;

  const int arow  = tid >> 1;
  const int kbase = (tid & 1) * 16;
  const int tok   = bm*128 + arow;
  const int bt    = tok / 196;
  const float* xrow = x + (size_t)(tok + bt + 1) * CIN + kbase;
  bf16_t* alds_dst = &Alds[arow*32 + kbase];

  const bf16_t* bsrc0 = W1 + (size_t)(bn*128 + (tid>>2))*CIN + (tid&3)*8;
  const bf16_t* bsrc1 = bsrc0 + (size_t)64*CIN;
  bf16_t* blds0 = &Blds[tid*8];
  bf16_t* blds1 = &Blds[(tid+256)*8];

  const int quad = lane >> 4;
  const int r16  = lane & 15;
  const int wm = (wave >> 1) * 64;
  const int wn = (wave & 1) * 64;

  f32x4 acc[4][4] = {};

  for (int k0 = 0; k0 < CIN; k0 += 32) {
    gl_lds16(bsrc0 + k0, blds0);
    gl_lds16(bsrc1 + k0, blds1);
    const float4* xp = (const float4*)(xrow + k0);
    float4 f0 = xp[0], f1 = xp[1], f2 = xp[2], f3 = xp[3];
    bf16x8 p0, p1;
    p0[0]=(bf16_t)f0.x; p0[1]=(bf16_t)f0.y; p0[2]=(bf16_t)f0.z; p0[3]=(bf16_t)f0.w;
    p0[4]=(bf16_t)f1.x; p0[5]=(bf16_t)f1.y; p0[6]=(bf16_t)f1.z; p0[7]=(bf16_t)f1.w;
    p1[0]=(bf16_t)f2.x; p1[1]=(bf16_t)f2.y; p1[2]=(bf16_t)f2.z; p1[3]=(bf16_t)f2.w;
    p1[4]=(bf16_t)f3.x; p1[5]=(bf16_t)f3.y; p1[6]=(bf16_t)f3.z; p1[7]=(bf16_t)f3.w;
    *(bf16x8*)alds_dst       = p0;
    *(bf16x8*)(alds_dst + 8) = p1;
    __syncthreads();
    bf16x8 af[4], bfr[4];
    #pragma unroll
    for (int mt = 0; mt < 4; mt++)
      af[mt] = *(const bf16x8*)&Alds[(wm + mt*16 + r16)*32 + quad*8];
    #pragma unroll
    for (int nt = 0; nt < 4; nt++)
      bfr[nt] = *(const bf16x8*)&Blds[(wn + nt*16 + r16)*32 + quad*8];
    #pragma unroll
    for (int mt = 0; mt < 4; mt++)
      #pragma unroll
      for (int nt = 0; nt < 4; nt++)
        acc[mt][nt] = __builtin_amdgcn_mfma_f32_16x16x32_bf16(af[mt], bfr[nt], acc[mt][nt], 0, 0, 0);
    __syncthreads();
  }

  #pragma unroll
  for (int nt = 0; nt < 4; nt++) {
    const int col = bn*128 + wn + nt*16 + r16;
    const float bias = fc1b[col];
    #pragma unroll
    for (int mt = 0; mt < 4; mt++) {
      const int row0 = bm*128 + wm + mt*16 + quad*4;
      #pragma unroll
      for (int rg = 0; rg < 4; rg++)
        H0[(size_t)(row0 + rg)*CA_ + col] = (bf16_t)(acc[mt][nt][rg] + bias);
    }
  }
}

// ---------------- fused conv v4: register-local temporal scatter, XCD-swizzled ----------------
// thread owns (b, hw, 8 channels, 8 consecutive t). 192 threads = 2 cols x 2 t-halves x 48 cg.
// grid: blockIdx.x = pair*8 + b  (batch b -> XCD b; 2.4 MB batch slab stays in XCD L2)
__global__ __launch_bounds__(192) void conv_kernel(
    const bf16_t* __restrict__ H0,
    const bf16_t* __restrict__ Wtb,   // [27][384] bf16
    const float* __restrict__ beff,   // [384]
    const float* __restrict__ pwt,    // [3][384]
    const float* __restrict__ pb,     // [384]
    bf16_t* __restrict__ Z) {
  __shared__ bf16_t Wlds[27*CA_];     // 20736 B
  __shared__ float  ybuf[2][2][CA_];  // 6144 B

  const int tid = threadIdx.x;
  {
    const uint4* src = (const uint4*)Wtb;
    uint4* dst = (uint4*)Wlds;
    #pragma unroll
    for (int i = 0; i < 7; i++) {
      int idx = tid + i*192;
      if (idx < 27*CA_/8) dst[idx] = src[idx];   // 1296 x 16B
    }
  }

  const int blk  = blockIdx.x;       // 0..783
  const int b    = blk & 7;
  const int pair = blk >> 3;         // 0..97
  const int cg   = tid % 48;
  const int ct   = tid / 48;         // 0..3
  const int col  = ct >> 1;
  const int th   = ct & 1;
  const int hw   = pair*2 + col;     // 0..195
  const int h    = hw / HH, w = hw % HH;
  const int c0   = cg * 8;
  const int t0   = th * 8;

  // init y with effective bias
  float y[8][8];
  {
    f32x4 bv0 = *(const f32x4*)(beff + c0);
    f32x4 bv1 = *(const f32x4*)(beff + c0 + 4);
    #pragma unroll
    for (int i = 0; i < 8; i++) {
      #pragma unroll
      for (int c = 0; c < 4; c++) { y[i][c] = bv0[c]; y[i][c+4] = bv1[c]; }
    }
  }

  __syncthreads();   // Wlds ready

  const size_t rowstride = (size_t)196*CA_;   // elements per t-step
  const bf16_t* base_t0 = H0 + ((size_t)(b*TT + t0)*196)*CA_ + c0;
  const int tau_e_off = th ? -1 : 8;          // the one extra valid tau (relative to t0)

  for (int j = 0; j < 9; j++) {
    const int dh = j / 3, dw = j - dh*3;
    const int h2 = h + dh - 1, w2 = w + dw - 1;
    const bool ok = ((unsigned)h2 < HH) && ((unsigned)w2 < HH);
    const int sp = ok ? (h2*HH + w2) : hw;    // clamped, always in-bounds
    const float m = ok ? 1.0f : 0.0f;

    const bf16x8 wv0 = *(const bf16x8*)&Wlds[(0*9+j)*CA_ + c0];
    const bf16x8 wv1 = *(const bf16x8*)&Wlds[(1*9+j)*CA_ + c0];
    const bf16x8 wv2 = *(const bf16x8*)&Wlds[(2*9+j)*CA_ + c0];
    float mw0[8], mw1[8], mw2[8];
    #pragma unroll
    for (int c = 0; c < 8; c++) {
      mw0[c] = m * (float)wv0[c];
      mw1[c] = m * (float)wv1[c];
      mw2[c] = m * (float)wv2[c];
    }

    const bf16_t* tp = base_t0 + (size_t)sp*CA_;
    bf16x8 gv[8];
    #pragma unroll
    for (int i = 0; i < 8; i++)
      gv[i] = *(const bf16x8*)(tp + (ptrdiff_t)i*(ptrdiff_t)rowstride);
    const bf16x8 ge = *(const bf16x8*)(tp + (ptrdiff_t)tau_e_off*(ptrdiff_t)rowstride);

    // interior taus: tau = t0+i contributes to y[i-1] (w2), y[i] (w1), y[i+1] (w0)
    #pragma unroll
    for (int i = 0; i < 8; i++) {
      float gf[8];
      #pragma unroll
      for (int c = 0; c < 8; c++) gf[c] = (float)gv[i][c];
      #pragma unroll
      for (int c = 0; c < 8; c++) y[i][c] += gf[c]*mw1[c];
      if (i > 0) {
        #pragma unroll
        for (int c = 0; c < 8; c++) y[i-1][c] += gf[c]*mw2[c];
      }
      if (i < 7) {
        #pragma unroll
        for (int c = 0; c < 8; c++) y[i+1][c] += gf[c]*mw0[c];
      }
    }
    // edge tau: th=0 -> tau=t0+8 feeds y[7] via w2 ; th=1 -> tau=t0-1 feeds y[0] via w0
    {
      float gf[8];
      #pragma unroll
      for (int c = 0; c < 8; c++) gf[c] = (float)ge[c];
      if (th) {
        #pragma unroll
        for (int c = 0; c < 8; c++) y[0][c] += gf[c]*mw0[c];
      } else {
        #pragma unroll
        for (int c = 0; c < 8; c++) y[7][c] += gf[c]*mw2[c];
      }
    }
  }

  // exchange the boundary y between t-halves (for the temporal proj)
  #pragma unroll
  for (int c = 0; c < 8; c++) ybuf[col][th][c0+c] = th ? y[0][c] : y[7][c];
  __syncthreads();
  float yedge[8];
  #pragma unroll
  for (int c = 0; c < 8; c++) yedge[c] = ybuf[col][1-th][c0+c];

  // proj weights
  float p0[8], p1[8], p2[8], pbv[8];
  {
    f32x4 a0 = *(const f32x4*)(pwt + 0*CA_ + c0), a1 = *(const f32x4*)(pwt + 0*CA_ + c0 + 4);
    f32x4 b0 = *(const f32x4*)(pwt + 1*CA_ + c0), b1 = *(const f32x4*)(pwt + 1*CA_ + c0 + 4);
    f32x4 d0 = *(const f32x4*)(pwt + 2*CA_ + c0), d1 = *(const f32x4*)(pwt + 2*CA_ + c0 + 4);
    f32x4 e0 = *(const f32x4*)(pb + c0),          e1 = *(const f32x4*)(pb + c0 + 4);
    #pragma unroll
    for (int c = 0; c < 4; c++) {
      p0[c]=a0[c]; p0[c+4]=a1[c];
      p1[c]=b0[c]; p1[c+4]=b1[c];
      p2[c]=d0[c]; p2[c+4]=d1[c];
      pbv[c]=e0[c]; pbv[c+4]=e1[c];
    }
  }

  bf16_t* zbase = Z + ((size_t)(b*TT + t0)*196 + hw)*CA_ + c0;
  #pragma unroll
  for (int i = 0; i < 8; i++) {
    bf16x8 zo;
    #pragma unroll
    for (int c = 0; c < 8; c++) {
      const float ym = (i > 0) ? y[i-1][c] : (th ? yedge[c] : 0.f);
      const float yp = (i < 7) ? y[i+1][c] : (th ? 0.f : yedge[c]);
      const float z  = y[i][c] + pbv[c] + p0[c]*ym + p1[c]*y[i][c] + p2[c]*yp;
      zo[c] = (bf16_t)z;
    }
    *(bf16x8*)(zbase + (size_t)i*rowstride) = zo;
  }
}

// ---------------- GEMM2: out[xrow,c] = x[xrow,c] + Z[tok,:] . fc2_w[c,:] + fc2_b[c] ----------------
__global__ __launch_bounds__(256) void gemm2_kernel(
    const bf16_t* __restrict__ Z, const bf16_t* __restrict__ W2,
    const float* __restrict__ fc2b, const float* __restrict__ x,
    float* __restrict__ out) {
  __shared__ bf16_t Alds[128*32];
  __shared__ bf16_t Blds[128*32];
  const int tid  = threadIdx.x;
  const int lane = tid & 63;
  const int wave = tid >> 6;
  const int bm = blockIdx.x, bn = blockIdx.y;

  const bf16_t* asrc0 = Z  + (size_t)(bm*128 + (tid>>2))*CA_ + (tid&3)*8;
  const bf16_t* asrc1 = asrc0 + (size_t)64*CA_;
  const bf16_t* bsrc0 = W2 + (size_t)(bn*128 + (tid>>2))*CA_ + (tid&3)*8;
  const bf16_t* bsrc1 = bsrc0 + (size_t)64*CA_;
  bf16_t* alds0 = &Alds[tid*8];
  bf16_t* alds1 = &Alds[(tid+256)*8];
  bf16_t* blds0 = &Blds[tid*8];
  bf16_t* blds1 = &Blds[(tid+256)*8];

  const int quad = lane >> 4;
  const int r16  = lane & 15;
  const int wm = (wave >> 1) * 64;
  const int wn = (wave & 1) * 64;

  f32x4 acc[4][4] = {};

  for (int k0 = 0; k0 < CA_; k0 += 32) {
    gl_lds16(asrc0 + k0, alds0);
    gl_lds16(asrc1 + k0, alds1);
    gl_lds16(bsrc0 + k0, blds0);
    gl_lds16(bsrc1 + k0, blds1);
    __syncthreads();
    bf16x8 af[4], bfr[4];
    #pragma unroll
    for (int mt = 0; mt < 4; mt++)
      af[mt] = *(const bf16x8*)&Alds[(wm + mt*16 + r16)*32 + quad*8];
    #pragma unroll
    for (int nt = 0; nt < 4; nt++)
      bfr[nt] = *(const bf16x8*)&Blds[(wn + nt*16 + r16)*32 + quad*8];
    #pragma unroll
    for (int mt = 0; mt < 4; mt++)
      #pragma unroll
      for (int nt = 0; nt < 4; nt++)
        acc[mt][nt] = __builtin_amdgcn_mfma_f32_16x16x32_bf16(af[mt], bfr[nt], acc[mt][nt], 0, 0, 0);
    __syncthreads();
  }

  #pragma unroll
  for (int nt = 0; nt < 4; nt++) {
    const int col = bn*128 + wn + nt*16 + r16;
    const float bias = fc2b[col];
    #pragma unroll
    for (int mt = 0; mt < 4; mt++) {
      #pragma unroll
      for (int rg = 0; rg < 4; rg++) {
        const int tok = bm*128 + wm + mt*16 + quad*4 + rg;
        const int bt  = tok / 196;
        const size_t o = (size_t)(tok + bt + 1)*CIN + col;
        out[o] = x[o] + acc[mt][nt][rg] + bias;
      }
    }
  }
}

extern "C" void kernel_launch(void* const* d_in, const int* in_sizes, int n_in,
                              void* d_out, int out_size, void* d_ws, size_t ws_size,
                              hipStream_t stream) {
  (void)in_sizes; (void)n_in; (void)out_size; (void)ws_size;
  const float* x    = (const float*)d_in[0];
  const float* fc1w = (const float*)d_in[1];
  const float* fc1b = (const float*)d_in[2];
  const float* c1w  = (const float*)d_in[3];
  const float* c1b  = (const float*)d_in[4];
  const float* c2w  = (const float*)d_in[5];
  const float* c2b  = (const float*)d_in[6];
  const float* c3w  = (const float*)d_in[7];
  const float* c3b  = (const float*)d_in[8];
  const float* pw   = (const float*)d_in[9];
  const float* pb   = (const float*)d_in[10];
  const float* fc2w = (const float*)d_in[11];
  const float* fc2b = (const float*)d_in[12];
  float* out = (float*)d_out;

  char* ws = (char*)d_ws;
  bf16_t* W1   = (bf16_t*)(ws);                    // 589824
  bf16_t* W2   = (bf16_t*)(ws + 589824);           // 589824
  bf16_t* Wtb  = (bf16_t*)(ws + 1179648);          // 27*384*2 = 20736
  float*  beff = (float*) (ws + 1200384);          // 1536
  float*  pwt  = (float*) (ws + 1201920);          // 4608
  bf16_t* H0   = (bf16_t*)(ws + 1206528);          // 19267584
  bf16_t* Z    = (bf16_t*)(ws + 20474112);         // 19267584
  // total ws use: 39741696 bytes

  prep_weights_kernel<<<dim3(2), dim3(192), 0, stream>>>(
      c1w, c1b, c2w, c2b, c3w, c3b, pw, Wtb, beff, pwt);
  convert_w_kernel<<<dim3(2688), dim3(256), 0, stream>>>(fc1w, fc2w, x, out, W1, W2);
  gemm1_kernel<<<dim3(196, 3), dim3(256), 0, stream>>>(x, W1, fc1b, H0);
  conv_kernel<<<dim3(784), dim3(192), 0, stream>>>(H0, Wtb, beff, pwt, pb, Z);
  gemm2_kernel<<<dim3(196, 6), dim3(256), 0, stream>>>(Z, W2, fc2b, x, out);
}